// Round 5
// baseline (227.825 us; speedup 1.0000x reference)
//
#include <hip/hip_runtime.h>

// Problem constants (fixed by reference)
#define BB 16
#define SS 1024
#define NIN 7
#define NHID 28
#define NH 7
#define DH 4

constexpr int ROWS = BB * SS;                 // 16384
constexpr int QKV_ELEMS = BB * NH * SS * DH;  // 458752 floats per tensor

// ---------------------------------------------------------------------------
// Kernel 1: QKV projection. inputs [B,S,7] @ W[7,28] + b -> Q,K,V in
// head-major layout [B][H][S][4]. Q pre-scaled by 1/sqrt(DH)=0.5.
// ---------------------------------------------------------------------------
__global__ __launch_bounds__(256) void k_proj(
    const float* __restrict__ inp,
    const float* __restrict__ Wq, const float* __restrict__ bq,
    const float* __restrict__ Wk, const float* __restrict__ bk,
    const float* __restrict__ Wv, const float* __restrict__ bv,
    float* __restrict__ Qo, float* __restrict__ Ko, float* __restrict__ Vo)
{
    __shared__ float  xs[256 * NIN];   // 7 KB: 256 rows of inputs
    __shared__ float4 w4[147];         // Wq(49) | Wk(49) | Wv(49) as float4
    __shared__ float4 b4[21];          // bq(7) | bk(7) | bv(7)

    const int tid  = threadIdx.x;
    const int row0 = blockIdx.x * 256;

    #pragma unroll
    for (int i = 0; i < NIN; ++i) xs[tid + 256 * i] = inp[row0 * NIN + tid + 256 * i];

    if (tid < 147) {
        const float* src = (tid < 49) ? Wq : (tid < 98) ? Wk : Wv;
        int off = (tid < 49) ? tid : (tid < 98) ? tid - 49 : tid - 98;
        w4[tid] = ((const float4*)src)[off];
    } else if (tid < 168) {
        int t = tid - 147;
        const float* src = (t < 7) ? bq : (t < 14) ? bk : bv;
        b4[t] = ((const float4*)src)[t % 7];
    }
    __syncthreads();

    const int r = row0 + tid;
    const int b = r >> 10, s = r & 1023;

    float x[NIN];
    #pragma unroll
    for (int i = 0; i < NIN; ++i) x[i] = xs[tid * NIN + i];

    float4 q[NH], k[NH], v[NH];
    #pragma unroll
    for (int j4 = 0; j4 < NH; ++j4) { q[j4] = b4[j4]; k[j4] = b4[7 + j4]; v[j4] = b4[14 + j4]; }

    #pragma unroll
    for (int i = 0; i < NIN; ++i) {
        const float xi = x[i];
        #pragma unroll
        for (int j4 = 0; j4 < NH; ++j4) {
            float4 wq = w4[i * 7 + j4];
            float4 wk = w4[49 + i * 7 + j4];
            float4 wv = w4[98 + i * 7 + j4];
            q[j4].x += xi * wq.x; q[j4].y += xi * wq.y; q[j4].z += xi * wq.z; q[j4].w += xi * wq.w;
            k[j4].x += xi * wk.x; k[j4].y += xi * wk.y; k[j4].z += xi * wk.z; k[j4].w += xi * wk.w;
            v[j4].x += xi * wv.x; v[j4].y += xi * wv.y; v[j4].z += xi * wv.z; v[j4].w += xi * wv.w;
        }
    }

    #pragma unroll
    for (int j4 = 0; j4 < NH; ++j4) {
        const int idx = (b * NH + j4) * SS + s;   // float4 index
        float4 qs = make_float4(0.5f * q[j4].x, 0.5f * q[j4].y, 0.5f * q[j4].z, 0.5f * q[j4].w);
        ((float4*)Qo)[idx] = qs;
        ((float4*)Ko)[idx] = k[j4];
        ((float4*)Vo)[idx] = v[j4];
    }
}

// ---------------------------------------------------------------------------
// Kernel 2: attention 1. Block = (b,h,qtile 256), 256 threads.
// Thread (ql=tid&31, kq=tid>>5) owns EIGHT queries {qt*256 + r*32 + ql}
// over a 128-key slice [kq*128, kq*128+128). Each K/V LDS read feeds 8
// queries (2x fewer LDS reads than R4). kq spans 2 values per wave ->
// 2 broadcast addresses (free per m136). Partial-merge buffers REUSE the
// K/V staging LDS (union): total 40KB -> 4 blocks/CU = 16 waves/CU
// (R4 was 52KB -> 3 blocks/CU).
// ---------------------------------------------------------------------------
__global__ __launch_bounds__(256) void k_attn1(
    const float* __restrict__ Qo, const float* __restrict__ Ko,
    const float* __restrict__ Vo, float* __restrict__ A)
{
    __shared__ char smem[40960];
    float4* Ksh  = (float4*)smem;             // [1024] 16 KB (phase 1)
    float4* Vsh  = (float4*)(smem + 16384);   // [1024] 16 KB (phase 1)
    float4* pacc = (float4*)smem;             // [2048] 32 KB (phase 2, overlaps K/V)
    float*  pl   = (float*)(smem + 32768);    // [2048]  8 KB (phase 2)

    const int bh  = blockIdx.x >> 2;
    const int qt  = blockIdx.x & 3;
    const int tid = threadIdx.x;

    const float4* Kg = (const float4*)Ko + (size_t)bh * SS;
    const float4* Vg = (const float4*)Vo + (size_t)bh * SS;
    #pragma unroll
    for (int i = 0; i < 4; ++i) {
        Ksh[tid + 256 * i] = Kg[tid + 256 * i];
        Vsh[tid + 256 * i] = Vg[tid + 256 * i];
    }
    __syncthreads();

    const int ql = tid & 31;
    const int kq = tid >> 5;          // 8-way key split

    float4 qv[8];
    #pragma unroll
    for (int r = 0; r < 8; ++r)
        qv[r] = ((const float4*)Qo)[(size_t)bh * SS + qt * 256 + r * 32 + ql];

    float4 acc[8];
    float  l[8];
    #pragma unroll
    for (int r = 0; r < 8; ++r) { acc[r] = make_float4(0.f, 0.f, 0.f, 0.f); l[r] = 0.f; }

    const int k0 = kq << 7;
    #pragma unroll 2
    for (int kk = k0; kk < k0 + 128; ++kk) {
        float4 kr = Ksh[kk];          // 2 broadcast addrs per wave (free)
        float4 vr = Vsh[kk];
        #pragma unroll
        for (int r = 0; r < 8; ++r) {
            float s = qv[r].x * kr.x + qv[r].y * kr.y + qv[r].z * kr.z + qv[r].w * kr.w;
            float p = __expf(s);
            l[r] += p;
            acc[r].x += p * vr.x; acc[r].y += p * vr.y;
            acc[r].z += p * vr.z; acc[r].w += p * vr.w;
        }
    }

    __syncthreads();   // all K/V reads done; smem reused as merge buffers
    #pragma unroll
    for (int r = 0; r < 8; ++r) {
        pacc[kq * 256 + r * 32 + ql] = acc[r];
        pl[kq * 256 + r * 32 + ql]   = l[r];
    }
    __syncthreads();

    // merge the 8 k-slices: thread tid owns query qt*256 + tid
    float4 a  = pacc[tid];
    float  ll = pl[tid];
    #pragma unroll
    for (int j = 1; j < 8; ++j) {
        float4 t = pacc[j * 256 + tid];
        a.x += t.x; a.y += t.y; a.z += t.z; a.w += t.w;
        ll += pl[j * 256 + tid];
    }
    const float inv = 1.f / ll;
    const int b = bh / NH, h = bh % NH;
    const int q = qt * 256 + tid;
    ((float4*)A)[(size_t)(b * SS + q) * NH + h] =
        make_float4(a.x * inv, a.y * inv, a.z * inv, a.w * inv);
}

// ---------------------------------------------------------------------------
// Kernel 3: LayerNorm(28) + FFN(28->7)+ReLU+residual -> out (output 0),
// then Q2 (row-major, pre-scaled 1/sqrt(7)) and K2 TRANSPOSED: K2T[b][d][s].
// ---------------------------------------------------------------------------
__global__ __launch_bounds__(256) void k_lnffn(
    const float* __restrict__ A, const float* __restrict__ inp,
    const float* __restrict__ lnw, const float* __restrict__ lnb,
    const float* __restrict__ W1, const float* __restrict__ b1,
    const float* __restrict__ Wq2, const float* __restrict__ bq2,
    const float* __restrict__ Wk2, const float* __restrict__ bk2,
    float* __restrict__ outp, float* __restrict__ Q2, float* __restrict__ K2T)
{
    const int r = blockIdx.x * 256 + threadIdx.x;

    float y[NHID];
    const float4* Ar = (const float4*)A + (size_t)r * 7;
    float mu = 0.f;
    #pragma unroll
    for (int j4 = 0; j4 < 7; ++j4) {
        float4 t = Ar[j4];
        y[4 * j4 + 0] = t.x; y[4 * j4 + 1] = t.y; y[4 * j4 + 2] = t.z; y[4 * j4 + 3] = t.w;
        mu += t.x + t.y + t.z + t.w;
    }
    mu *= (1.f / NHID);
    float var = 0.f;
    #pragma unroll
    for (int j = 0; j < NHID; ++j) { float d = y[j] - mu; var += d * d; }
    var *= (1.f / NHID);
    const float rstd = rsqrtf(var + 1e-5f);
    #pragma unroll
    for (int j = 0; j < NHID; ++j) y[j] = (y[j] - mu) * rstd * lnw[j] + lnb[j];

    float o[NIN];
    #pragma unroll
    for (int i = 0; i < NIN; ++i) {
        float a = b1[i];
        #pragma unroll
        for (int j = 0; j < NHID; ++j) a += y[j] * W1[j * NIN + i];
        o[i] = fmaxf(a, 0.f) + inp[r * NIN + i];
        outp[r * NIN + i] = o[i];
    }

    const float rs7 = 0.3779644730092272f;  // 1/sqrt(7)
    const int b = r >> 10, s = r & 1023;
    float* K2Tb = K2T + ((size_t)b * NHID) * SS + s;
    float4* Q2r = (float4*)Q2 + (size_t)r * 7;
    #pragma unroll
    for (int j4 = 0; j4 < 7; ++j4) {
        float qq[4];
        #pragma unroll
        for (int c = 0; c < 4; ++c) {
            int j = 4 * j4 + c;
            float aq = bq2[j], ak = bk2[j];
            #pragma unroll
            for (int i = 0; i < NIN; ++i) {
                aq += o[i] * Wq2[i * NHID + j];
                ak += o[i] * Wk2[i * NHID + j];
            }
            qq[c] = aq * rs7;
            K2Tb[(size_t)j * SS] = ak;      // coalesced per-j
        }
        Q2r[j4] = make_float4(qq[0], qq[1], qq[2], qq[3]);
    }
}

// ---------------------------------------------------------------------------
// Kernel 4: attention 2 weights. Wave-autonomous, QR=4 rows/wave (keeps
// K2T L2 re-read at 459 MB), but keys are processed in TWO 512-key chunks:
// chunk 0's p (32 VGPRs) is stashed to wave-private LDS while chunk 1 is
// computed, halving the live register footprint that made R4 sit at
// 208 VGPR / 2 waves-per-SIMD. LDS 34 KB -> 4 blocks/CU = 16 waves/CU.
// Row sum accumulated across chunks, butterfly-reduced, stores per wave.
// ---------------------------------------------------------------------------
#define QR 4
__global__ __launch_bounds__(256) void k_attn2(
    const float* __restrict__ Q2, const float* __restrict__ K2T,
    float* __restrict__ out2)
{
    __shared__ float  q2s[16 * NHID];            // 1792 B
    __shared__ float4 pst[QR * 2 * 4 * 64];      // 32 KB: [wid][r][jj][lane]

    const int tid  = threadIdx.x;
    const int lane = tid & 63;
    const int wid  = tid >> 6;
    const int row0 = blockIdx.x * 16;            // global row = b*1024 + s
    const int b    = row0 >> 10;

    if (tid < 112) ((float4*)q2s)[tid] = ((const float4*)Q2)[(size_t)row0 * 7 + tid];
    __syncthreads();

    const float*  qw  = q2s + wid * QR * NHID;   // this wave's 4 rows
    const float4* K2b = (const float4*)(K2T + (size_t)b * NHID * SS);  // [28][256] f4

    float rsum[QR] = {0.f, 0.f, 0.f, 0.f};
    float4 p[QR][2];

    #pragma unroll
    for (int chunk = 0; chunk < 2; ++chunk) {
        #pragma unroll
        for (int r = 0; r < QR; ++r) {
            p[r][0] = make_float4(0.f, 0.f, 0.f, 0.f);
            p[r][1] = make_float4(0.f, 0.f, 0.f, 0.f);
        }
        #pragma unroll
        for (int d4 = 0; d4 < 7; ++d4) {
            float4 qv[QR];
            #pragma unroll
            for (int r = 0; r < QR; ++r) qv[r] = ((const float4*)qw)[r * 7 + d4];
            #pragma unroll
            for (int dd = 0; dd < 4; ++dd) {
                const int d = d4 * 4 + dd;
                float4 kt0 = K2b[d * 256 + (chunk * 2 + 0) * 64 + lane];
                float4 kt1 = K2b[d * 256 + (chunk * 2 + 1) * 64 + lane];
                #pragma unroll
                for (int r = 0; r < QR; ++r) {
                    const float qd = (dd == 0) ? qv[r].x : (dd == 1) ? qv[r].y
                                   : (dd == 2) ? qv[r].z : qv[r].w;
                    p[r][0].x += qd * kt0.x; p[r][0].y += qd * kt0.y;
                    p[r][0].z += qd * kt0.z; p[r][0].w += qd * kt0.w;
                    p[r][1].x += qd * kt1.x; p[r][1].y += qd * kt1.y;
                    p[r][1].z += qd * kt1.z; p[r][1].w += qd * kt1.w;
                }
            }
        }
        #pragma unroll
        for (int r = 0; r < QR; ++r) {
            #pragma unroll
            for (int jj = 0; jj < 2; ++jj) {
                p[r][jj].x = __expf(p[r][jj].x);
                p[r][jj].y = __expf(p[r][jj].y);
                p[r][jj].z = __expf(p[r][jj].z);
                p[r][jj].w = __expf(p[r][jj].w);
                rsum[r] += p[r][jj].x + p[r][jj].y + p[r][jj].z + p[r][jj].w;
            }
        }
        if (chunk == 0) {
            #pragma unroll
            for (int r = 0; r < QR; ++r) {
                pst[((wid * QR + r) * 2 + 0) * 64 + lane] = p[r][0];
                pst[((wid * QR + r) * 2 + 1) * 64 + lane] = p[r][1];
            }
        }
    }

    #pragma unroll
    for (int r = 0; r < QR; ++r) {
        float sum = rsum[r];
        #pragma unroll
        for (int off = 1; off < 64; off <<= 1) sum += __shfl_xor(sum, off);
        const float iv = 1.f / sum;
        float4* orow = (float4*)(out2 + ((size_t)row0 + wid * QR + r) * SS);
        float4 a0 = pst[((wid * QR + r) * 2 + 0) * 64 + lane];   // chunk0 j=0
        float4 a1 = pst[((wid * QR + r) * 2 + 1) * 64 + lane];   // chunk0 j=1
        orow[0 * 64 + lane] = make_float4(a0.x * iv, a0.y * iv, a0.z * iv, a0.w * iv);
        orow[1 * 64 + lane] = make_float4(a1.x * iv, a1.y * iv, a1.z * iv, a1.w * iv);
        orow[2 * 64 + lane] = make_float4(p[r][0].x * iv, p[r][0].y * iv,
                                          p[r][0].z * iv, p[r][0].w * iv);
        orow[3 * 64 + lane] = make_float4(p[r][1].x * iv, p[r][1].y * iv,
                                          p[r][1].z * iv, p[r][1].w * iv);
    }
}

// ---------------------------------------------------------------------------
extern "C" void kernel_launch(void* const* d_in, const int* in_sizes, int n_in,
                              void* d_out, int out_size, void* d_ws, size_t ws_size,
                              hipStream_t stream) {
    const float* inp = (const float*)d_in[0];
    const float* Wq  = (const float*)d_in[1];
    const float* bq  = (const float*)d_in[2];
    const float* Wk  = (const float*)d_in[3];
    const float* bk  = (const float*)d_in[4];
    const float* Wv  = (const float*)d_in[5];
    const float* bv  = (const float*)d_in[6];
    const float* lnw = (const float*)d_in[7];
    const float* lnb = (const float*)d_in[8];
    const float* W1  = (const float*)d_in[9];
    const float* b1  = (const float*)d_in[10];
    const float* Wq2 = (const float*)d_in[11];
    const float* bq2 = (const float*)d_in[12];
    const float* Wk2 = (const float*)d_in[13];
    const float* bk2 = (const float*)d_in[14];

    float* out0 = (float*)d_out;                 // [16,1024,7]
    float* out2 = out0 + ROWS * NIN;             // [16,1024,1024]

    float* ws = (float*)d_ws;
    float* Qo  = ws;
    float* Ko  = ws + (size_t)QKV_ELEMS;
    float* Vo  = ws + (size_t)2 * QKV_ELEMS;
    float* A   = ws + (size_t)3 * QKV_ELEMS;
    float* Q2  = ws + (size_t)4 * QKV_ELEMS;
    float* K2T = ws + (size_t)5 * QKV_ELEMS;     // [B,28,S]

    k_proj <<<ROWS / 256, 256, 0, stream>>>(inp, Wq, bq, Wk, bk, Wv, bv, Qo, Ko, Vo);
    k_attn1<<<BB * NH * 4, 256, 0, stream>>>(Qo, Ko, Vo, A);
    k_lnffn<<<ROWS / 256, 256, 0, stream>>>(A, inp, lnw, lnb, W1, b1,
                                            Wq2, bq2, Wk2, bk2, out0, Q2, K2T);
    k_attn2<<<ROWS / 16, 256, 0, stream>>>(Q2, K2T, out2);
}

// Round 6
// 186.744 us; speedup vs baseline: 1.2200x; 1.2200x over previous
//
#include <hip/hip_runtime.h>

// Problem constants (fixed by reference)
#define BB 16
#define SS 1024
#define NIN 7
#define NHID 28
#define NH 7
#define DH 4

constexpr int ROWS = BB * SS;                 // 16384
constexpr int QKV_ELEMS = BB * NH * SS * DH;  // 458752 floats per tensor

// ---------------------------------------------------------------------------
// Kernel 1: QKV projection. inputs [B,S,7] @ W[7,28] + b -> Q,K,V in
// head-major layout [B][H][S][4]. Q pre-scaled by 1/sqrt(DH)=0.5.
// ---------------------------------------------------------------------------
__global__ __launch_bounds__(256) void k_proj(
    const float* __restrict__ inp,
    const float* __restrict__ Wq, const float* __restrict__ bq,
    const float* __restrict__ Wk, const float* __restrict__ bk,
    const float* __restrict__ Wv, const float* __restrict__ bv,
    float* __restrict__ Qo, float* __restrict__ Ko, float* __restrict__ Vo)
{
    __shared__ float  xs[256 * NIN];   // 7 KB: 256 rows of inputs
    __shared__ float4 w4[147];         // Wq(49) | Wk(49) | Wv(49) as float4
    __shared__ float4 b4[21];          // bq(7) | bk(7) | bv(7)

    const int tid  = threadIdx.x;
    const int row0 = blockIdx.x * 256;

    #pragma unroll
    for (int i = 0; i < NIN; ++i) xs[tid + 256 * i] = inp[row0 * NIN + tid + 256 * i];

    if (tid < 147) {
        const float* src = (tid < 49) ? Wq : (tid < 98) ? Wk : Wv;
        int off = (tid < 49) ? tid : (tid < 98) ? tid - 49 : tid - 98;
        w4[tid] = ((const float4*)src)[off];
    } else if (tid < 168) {
        int t = tid - 147;
        const float* src = (t < 7) ? bq : (t < 14) ? bk : bv;
        b4[t] = ((const float4*)src)[t % 7];
    }
    __syncthreads();

    const int r = row0 + tid;
    const int b = r >> 10, s = r & 1023;

    float x[NIN];
    #pragma unroll
    for (int i = 0; i < NIN; ++i) x[i] = xs[tid * NIN + i];

    float4 q[NH], k[NH], v[NH];
    #pragma unroll
    for (int j4 = 0; j4 < NH; ++j4) { q[j4] = b4[j4]; k[j4] = b4[7 + j4]; v[j4] = b4[14 + j4]; }

    #pragma unroll
    for (int i = 0; i < NIN; ++i) {
        const float xi = x[i];
        #pragma unroll
        for (int j4 = 0; j4 < NH; ++j4) {
            float4 wq = w4[i * 7 + j4];
            float4 wk = w4[49 + i * 7 + j4];
            float4 wv = w4[98 + i * 7 + j4];
            q[j4].x += xi * wq.x; q[j4].y += xi * wq.y; q[j4].z += xi * wq.z; q[j4].w += xi * wq.w;
            k[j4].x += xi * wk.x; k[j4].y += xi * wk.y; k[j4].z += xi * wk.z; k[j4].w += xi * wk.w;
            v[j4].x += xi * wv.x; v[j4].y += xi * wv.y; v[j4].z += xi * wv.z; v[j4].w += xi * wv.w;
        }
    }

    #pragma unroll
    for (int j4 = 0; j4 < NH; ++j4) {
        const int idx = (b * NH + j4) * SS + s;   // float4 index
        float4 qs = make_float4(0.5f * q[j4].x, 0.5f * q[j4].y, 0.5f * q[j4].z, 0.5f * q[j4].w);
        ((float4*)Qo)[idx] = qs;
        ((float4*)Ko)[idx] = k[j4];
        ((float4*)Vo)[idx] = v[j4];
    }
}

// ---------------------------------------------------------------------------
// Kernel 2: attention 1. Block = (b,h,qtile 128), 256 threads, 896 blocks
// (3.5 blocks/CU -- smooths R4/R5's 1.75/CU 2:1 tail). Thread (ql=tid&31,
// kq=tid>>5) owns FOUR queries {qt*128 + r*32 + ql} over the 128-key slice
// [kq*128, kq*128+128). Each K/V LDS read feeds 4 queries; 2 broadcast
// addrs per wave (free, m136). Merge buffers overlay the K/V staging LDS
// after compute: 32 KB total -> ~5 blocks/CU capacity.
// ---------------------------------------------------------------------------
__global__ __launch_bounds__(256) void k_attn1(
    const float* __restrict__ Qo, const float* __restrict__ Ko,
    const float* __restrict__ Vo, float* __restrict__ A)
{
    __shared__ char smem[32768];
    float4* Ksh  = (float4*)smem;             // [1024] 16 KB (phase 1)
    float4* Vsh  = (float4*)(smem + 16384);   // [1024] 16 KB (phase 1)
    float4* pacc = (float4*)smem;             // [8][128] 8 KB (phase 2 overlay)
    float*  pl   = (float*)(smem + 16384);    // [8][128] 4 KB (phase 2 overlay)

    const int bh  = blockIdx.x >> 3;
    const int qt  = blockIdx.x & 7;
    const int tid = threadIdx.x;

    const float4* Kg = (const float4*)Ko + (size_t)bh * SS;
    const float4* Vg = (const float4*)Vo + (size_t)bh * SS;
    #pragma unroll
    for (int i = 0; i < 4; ++i) {
        Ksh[tid + 256 * i] = Kg[tid + 256 * i];
        Vsh[tid + 256 * i] = Vg[tid + 256 * i];
    }
    __syncthreads();

    const int ql = tid & 31;
    const int kq = tid >> 5;          // 8-way key split

    float4 qv[4];
    #pragma unroll
    for (int r = 0; r < 4; ++r)
        qv[r] = ((const float4*)Qo)[(size_t)bh * SS + qt * 128 + r * 32 + ql];

    float4 acc[4];
    float  l[4];
    #pragma unroll
    for (int r = 0; r < 4; ++r) { acc[r] = make_float4(0.f, 0.f, 0.f, 0.f); l[r] = 0.f; }

    const int k0 = kq << 7;
    #pragma unroll 2
    for (int kk = k0; kk < k0 + 128; ++kk) {
        float4 kr = Ksh[kk];          // 2 broadcast addrs per wave (free)
        float4 vr = Vsh[kk];
        #pragma unroll
        for (int r = 0; r < 4; ++r) {
            float s = qv[r].x * kr.x + qv[r].y * kr.y + qv[r].z * kr.z + qv[r].w * kr.w;
            float p = __expf(s);
            l[r] += p;
            acc[r].x += p * vr.x; acc[r].y += p * vr.y;
            acc[r].z += p * vr.z; acc[r].w += p * vr.w;
        }
    }

    __syncthreads();   // all K/V reads done; smem reused as merge buffers
    #pragma unroll
    for (int r = 0; r < 4; ++r) {
        pacc[kq * 128 + r * 32 + ql] = acc[r];
        pl[kq * 128 + r * 32 + ql]   = l[r];
    }
    __syncthreads();

    // merge the 8 k-slices: threads 0..127 own query qt*128 + tid
    if (tid < 128) {
        float4 a  = pacc[tid];
        float  ll = pl[tid];
        #pragma unroll
        for (int j = 1; j < 8; ++j) {
            float4 t = pacc[j * 128 + tid];
            a.x += t.x; a.y += t.y; a.z += t.z; a.w += t.w;
            ll += pl[j * 128 + tid];
        }
        const float inv = 1.f / ll;
        const int b = bh / NH, h = bh % NH;
        const int q = qt * 128 + tid;
        ((float4*)A)[(size_t)(b * SS + q) * NH + h] =
            make_float4(a.x * inv, a.y * inv, a.z * inv, a.w * inv);
    }
}

// ---------------------------------------------------------------------------
// Kernel 3: LayerNorm(28) + FFN(28->7)+ReLU+residual -> out (output 0),
// then Q2 (row-major, pre-scaled 1/sqrt(7)) and K2 TRANSPOSED: K2T[b][d][s].
// ---------------------------------------------------------------------------
__global__ __launch_bounds__(256) void k_lnffn(
    const float* __restrict__ A, const float* __restrict__ inp,
    const float* __restrict__ lnw, const float* __restrict__ lnb,
    const float* __restrict__ W1, const float* __restrict__ b1,
    const float* __restrict__ Wq2, const float* __restrict__ bq2,
    const float* __restrict__ Wk2, const float* __restrict__ bk2,
    float* __restrict__ outp, float* __restrict__ Q2, float* __restrict__ K2T)
{
    const int r = blockIdx.x * 256 + threadIdx.x;

    float y[NHID];
    const float4* Ar = (const float4*)A + (size_t)r * 7;
    float mu = 0.f;
    #pragma unroll
    for (int j4 = 0; j4 < 7; ++j4) {
        float4 t = Ar[j4];
        y[4 * j4 + 0] = t.x; y[4 * j4 + 1] = t.y; y[4 * j4 + 2] = t.z; y[4 * j4 + 3] = t.w;
        mu += t.x + t.y + t.z + t.w;
    }
    mu *= (1.f / NHID);
    float var = 0.f;
    #pragma unroll
    for (int j = 0; j < NHID; ++j) { float d = y[j] - mu; var += d * d; }
    var *= (1.f / NHID);
    const float rstd = rsqrtf(var + 1e-5f);
    #pragma unroll
    for (int j = 0; j < NHID; ++j) y[j] = (y[j] - mu) * rstd * lnw[j] + lnb[j];

    float o[NIN];
    #pragma unroll
    for (int i = 0; i < NIN; ++i) {
        float a = b1[i];
        #pragma unroll
        for (int j = 0; j < NHID; ++j) a += y[j] * W1[j * NIN + i];
        o[i] = fmaxf(a, 0.f) + inp[r * NIN + i];
        outp[r * NIN + i] = o[i];
    }

    const float rs7 = 0.3779644730092272f;  // 1/sqrt(7)
    const int b = r >> 10, s = r & 1023;
    float* K2Tb = K2T + ((size_t)b * NHID) * SS + s;
    float4* Q2r = (float4*)Q2 + (size_t)r * 7;
    #pragma unroll
    for (int j4 = 0; j4 < 7; ++j4) {
        float qq[4];
        #pragma unroll
        for (int c = 0; c < 4; ++c) {
            int j = 4 * j4 + c;
            float aq = bq2[j], ak = bk2[j];
            #pragma unroll
            for (int i = 0; i < NIN; ++i) {
                aq += o[i] * Wq2[i * NHID + j];
                ak += o[i] * Wk2[i * NHID + j];
            }
            qq[c] = aq * rs7;
            K2Tb[(size_t)j * SS] = ak;      // coalesced per-j
        }
        Q2r[j4] = make_float4(qq[0], qq[1], qq[2], qq[3]);
    }
}

// ---------------------------------------------------------------------------
// Kernel 4: attention 2 weights. Wave-autonomous, 4 rows/wave (R4 structure:
// p[4 rows][16 keys] = 64 VGPRs, 57.6us at 208 VGPR / 2 waves/SIMD).
// R6 changes vs R4: (a) the 28-dim loop is DYNAMIC -- q read per-iter from
// LDS as a scalar broadcast, so the compiler has no 28-deep unrolled region
// to software-pipeline into 200+ VGPRs; (b) __launch_bounds__(256,4) caps
// at 128 VGPRs (~96 architectural need + headroom; R3's failure was a
// 64-cap against a 120 need). If FETCH_SIZE balloons -> it spilled -> revert.
// ---------------------------------------------------------------------------
#define QR 4
__global__ __launch_bounds__(256, 4) void k_attn2(
    const float* __restrict__ Q2, const float* __restrict__ K2T,
    float* __restrict__ out2)
{
    __shared__ float q2s[16 * NHID];   // 1792 B

    const int tid  = threadIdx.x;
    const int lane = tid & 63;
    const int wid  = tid >> 6;
    const int row0 = blockIdx.x * 16;          // global row = b*1024 + s
    const int b    = row0 >> 10;

    if (tid < 112) ((float4*)q2s)[tid] = ((const float4*)Q2)[(size_t)row0 * 7 + tid];
    __syncthreads();

    const float*  qw  = q2s + wid * QR * NHID;              // this wave's 4 rows
    const float4* K2b = (const float4*)(K2T + (size_t)b * NHID * SS);  // [28][256] f4

    float4 p0[QR], p1[QR], p2[QR], p3[QR];     // p[r][j]: 64 VGPRs
    #pragma unroll
    for (int r = 0; r < QR; ++r) {
        p0[r] = make_float4(0.f, 0.f, 0.f, 0.f);
        p1[r] = make_float4(0.f, 0.f, 0.f, 0.f);
        p2[r] = make_float4(0.f, 0.f, 0.f, 0.f);
        p3[r] = make_float4(0.f, 0.f, 0.f, 0.f);
    }

    #pragma unroll 2
    for (int d = 0; d < NHID; ++d) {
        float4 kt0 = K2b[d * 256 +       lane];
        float4 kt1 = K2b[d * 256 +  64 + lane];
        float4 kt2 = K2b[d * 256 + 128 + lane];
        float4 kt3 = K2b[d * 256 + 192 + lane];
        #pragma unroll
        for (int r = 0; r < QR; ++r) {
            const float qd = qw[r * NHID + d];  // LDS scalar broadcast
            p0[r].x += qd * kt0.x; p0[r].y += qd * kt0.y;
            p0[r].z += qd * kt0.z; p0[r].w += qd * kt0.w;
            p1[r].x += qd * kt1.x; p1[r].y += qd * kt1.y;
            p1[r].z += qd * kt1.z; p1[r].w += qd * kt1.w;
            p2[r].x += qd * kt2.x; p2[r].y += qd * kt2.y;
            p2[r].z += qd * kt2.z; p2[r].w += qd * kt2.w;
            p3[r].x += qd * kt3.x; p3[r].y += qd * kt3.y;
            p3[r].z += qd * kt3.z; p3[r].w += qd * kt3.w;
        }
    }

    #pragma unroll
    for (int r = 0; r < QR; ++r) {
        p0[r].x = __expf(p0[r].x); p0[r].y = __expf(p0[r].y);
        p0[r].z = __expf(p0[r].z); p0[r].w = __expf(p0[r].w);
        p1[r].x = __expf(p1[r].x); p1[r].y = __expf(p1[r].y);
        p1[r].z = __expf(p1[r].z); p1[r].w = __expf(p1[r].w);
        p2[r].x = __expf(p2[r].x); p2[r].y = __expf(p2[r].y);
        p2[r].z = __expf(p2[r].z); p2[r].w = __expf(p2[r].w);
        p3[r].x = __expf(p3[r].x); p3[r].y = __expf(p3[r].y);
        p3[r].z = __expf(p3[r].z); p3[r].w = __expf(p3[r].w);
        float sum = p0[r].x + p0[r].y + p0[r].z + p0[r].w
                  + p1[r].x + p1[r].y + p1[r].z + p1[r].w
                  + p2[r].x + p2[r].y + p2[r].z + p2[r].w
                  + p3[r].x + p3[r].y + p3[r].z + p3[r].w;
        #pragma unroll
        for (int off = 1; off < 64; off <<= 1) sum += __shfl_xor(sum, off);
        const float iv = 1.f / sum;
        float4* orow = (float4*)(out2 + ((size_t)row0 + wid * QR + r) * SS);
        orow[       lane] = make_float4(p0[r].x * iv, p0[r].y * iv, p0[r].z * iv, p0[r].w * iv);
        orow[ 64 + lane] = make_float4(p1[r].x * iv, p1[r].y * iv, p1[r].z * iv, p1[r].w * iv);
        orow[128 + lane] = make_float4(p2[r].x * iv, p2[r].y * iv, p2[r].z * iv, p2[r].w * iv);
        orow[192 + lane] = make_float4(p3[r].x * iv, p3[r].y * iv, p3[r].z * iv, p3[r].w * iv);
    }
}

// ---------------------------------------------------------------------------
extern "C" void kernel_launch(void* const* d_in, const int* in_sizes, int n_in,
                              void* d_out, int out_size, void* d_ws, size_t ws_size,
                              hipStream_t stream) {
    const float* inp = (const float*)d_in[0];
    const float* Wq  = (const float*)d_in[1];
    const float* bq  = (const float*)d_in[2];
    const float* Wk  = (const float*)d_in[3];
    const float* bk  = (const float*)d_in[4];
    const float* Wv  = (const float*)d_in[5];
    const float* bv  = (const float*)d_in[6];
    const float* lnw = (const float*)d_in[7];
    const float* lnb = (const float*)d_in[8];
    const float* W1  = (const float*)d_in[9];
    const float* b1  = (const float*)d_in[10];
    const float* Wq2 = (const float*)d_in[11];
    const float* bq2 = (const float*)d_in[12];
    const float* Wk2 = (const float*)d_in[13];
    const float* bk2 = (const float*)d_in[14];

    float* out0 = (float*)d_out;                 // [16,1024,7]
    float* out2 = out0 + ROWS * NIN;             // [16,1024,1024]

    float* ws = (float*)d_ws;
    float* Qo  = ws;
    float* Ko  = ws + (size_t)QKV_ELEMS;
    float* Vo  = ws + (size_t)2 * QKV_ELEMS;
    float* A   = ws + (size_t)3 * QKV_ELEMS;
    float* Q2  = ws + (size_t)4 * QKV_ELEMS;
    float* K2T = ws + (size_t)5 * QKV_ELEMS;     // [B,28,S]

    k_proj <<<ROWS / 256, 256, 0, stream>>>(inp, Wq, bq, Wk, bk, Wv, bv, Qo, Ko, Vo);
    k_attn1<<<BB * NH * 8, 256, 0, stream>>>(Qo, Ko, Vo, A);
    k_lnffn<<<ROWS / 256, 256, 0, stream>>>(A, inp, lnw, lnb, W1, b1,
                                            Wq2, bq2, Wk2, bk2, out0, Q2, K2T);
    k_attn2<<<ROWS / 16, 256, 0, stream>>>(Q2, K2T, out2);
}

// Round 8
// 183.964 us; speedup vs baseline: 1.2384x; 1.0151x over previous
//
#include <hip/hip_runtime.h>

// Problem constants (fixed by reference)
#define BB 16
#define SS 1024
#define NIN 7
#define NHID 28
#define NH 7
#define DH 4

// Raw 2^x (v_exp_f32). NOTE: __exp2f does NOT exist in HIP device code
// (R7 compile failure -- glibc math.h macro collision). exp(x) == exp2(x*log2e);
// the log2e factor is folded into the Q / Q2 projection scales.
#define EXP2F(x) __builtin_amdgcn_exp2f(x)

constexpr int ROWS = BB * SS;                 // 16384
constexpr int QKV_ELEMS = BB * NH * SS * DH;  // 458752 floats per tensor

// ---------------------------------------------------------------------------
// Kernel 1: QKV projection. inputs [B,S,7] @ W[7,28] + b -> Q,K,V in
// head-major layout [B][H][S][4]. Q pre-scaled by (1/sqrt(DH)) * log2(e)
// so attention-1 can use exp2 instead of exp (saves one v_mul per pair).
// ---------------------------------------------------------------------------
__global__ __launch_bounds__(256) void k_proj(
    const float* __restrict__ inp,
    const float* __restrict__ Wq, const float* __restrict__ bq,
    const float* __restrict__ Wk, const float* __restrict__ bk,
    const float* __restrict__ Wv, const float* __restrict__ bv,
    float* __restrict__ Qo, float* __restrict__ Ko, float* __restrict__ Vo)
{
    __shared__ float  xs[256 * NIN];   // 7 KB: 256 rows of inputs
    __shared__ float4 w4[147];         // Wq(49) | Wk(49) | Wv(49) as float4
    __shared__ float4 b4[21];          // bq(7) | bk(7) | bv(7)

    const int tid  = threadIdx.x;
    const int row0 = blockIdx.x * 256;

    #pragma unroll
    for (int i = 0; i < NIN; ++i) xs[tid + 256 * i] = inp[row0 * NIN + tid + 256 * i];

    if (tid < 147) {
        const float* src = (tid < 49) ? Wq : (tid < 98) ? Wk : Wv;
        int off = (tid < 49) ? tid : (tid < 98) ? tid - 49 : tid - 98;
        w4[tid] = ((const float4*)src)[off];
    } else if (tid < 168) {
        int t = tid - 147;
        const float* src = (t < 7) ? bq : (t < 14) ? bk : bv;
        b4[t] = ((const float4*)src)[t % 7];
    }
    __syncthreads();

    const int r = row0 + tid;
    const int b = r >> 10, s = r & 1023;

    float x[NIN];
    #pragma unroll
    for (int i = 0; i < NIN; ++i) x[i] = xs[tid * NIN + i];

    float4 q[NH], k[NH], v[NH];
    #pragma unroll
    for (int j4 = 0; j4 < NH; ++j4) { q[j4] = b4[j4]; k[j4] = b4[7 + j4]; v[j4] = b4[14 + j4]; }

    #pragma unroll
    for (int i = 0; i < NIN; ++i) {
        const float xi = x[i];
        #pragma unroll
        for (int j4 = 0; j4 < NH; ++j4) {
            float4 wq = w4[i * 7 + j4];
            float4 wk = w4[49 + i * 7 + j4];
            float4 wv = w4[98 + i * 7 + j4];
            q[j4].x += xi * wq.x; q[j4].y += xi * wq.y; q[j4].z += xi * wq.z; q[j4].w += xi * wq.w;
            k[j4].x += xi * wk.x; k[j4].y += xi * wk.y; k[j4].z += xi * wk.z; k[j4].w += xi * wk.w;
            v[j4].x += xi * wv.x; v[j4].y += xi * wv.y; v[j4].z += xi * wv.z; v[j4].w += xi * wv.w;
        }
    }

    const float qs_scale = 0.5f * 1.4426950408889634f;  // (1/sqrt(4)) * log2(e)
    #pragma unroll
    for (int j4 = 0; j4 < NH; ++j4) {
        const int idx = (b * NH + j4) * SS + s;   // float4 index
        float4 qs = make_float4(qs_scale * q[j4].x, qs_scale * q[j4].y,
                                qs_scale * q[j4].z, qs_scale * q[j4].w);
        ((float4*)Qo)[idx] = qs;
        ((float4*)Ko)[idx] = k[j4];
        ((float4*)Vo)[idx] = v[j4];
    }
}

// ---------------------------------------------------------------------------
// Kernel 2: attention 1. Block = (b,h,qtile 128), 512 threads (8 waves),
// 896 blocks. Occupancy: LDS 32KB -> 4-5 blocks/CU x 8 waves ~= 28-32
// waves/CU (R6 had 4-wave blocks -> only ~14 waves/CU, VALUBusy 61%).
// Thread (ql=tid&63, kq=tid>>6) owns TWO queries {qt*128 + ql, +64} over
// the 128-key slice [kq*128, kq*128+128). kq is wave-uniform -> single
// LDS broadcast address per read. Scores use exp2 (Q pre-scaled by log2e).
// Merge buffers overlay the K/V staging LDS after compute.
// ---------------------------------------------------------------------------
__global__ __launch_bounds__(512) void k_attn1(
    const float* __restrict__ Qo, const float* __restrict__ Ko,
    const float* __restrict__ Vo, float* __restrict__ A)
{
    __shared__ char smem[32768];
    float4* Ksh  = (float4*)smem;             // [1024] 16 KB (phase 1)
    float4* Vsh  = (float4*)(smem + 16384);   // [1024] 16 KB (phase 1)
    float4* pacc = (float4*)smem;             // [8][128] 8 KB (phase 2 overlay)
    float*  pl   = (float*)(smem + 16384);    // [8][128] 4 KB (phase 2 overlay)

    const int bh  = blockIdx.x >> 3;
    const int qt  = blockIdx.x & 7;
    const int tid = threadIdx.x;

    const float4* Kg = (const float4*)Ko + (size_t)bh * SS;
    const float4* Vg = (const float4*)Vo + (size_t)bh * SS;
    #pragma unroll
    for (int i = 0; i < 2; ++i) {
        Ksh[tid + 512 * i] = Kg[tid + 512 * i];
        Vsh[tid + 512 * i] = Vg[tid + 512 * i];
    }
    __syncthreads();

    const int ql = tid & 63;
    const int kq = tid >> 6;          // wave id; uniform within wave

    float4 qv[2];
    #pragma unroll
    for (int r = 0; r < 2; ++r)
        qv[r] = ((const float4*)Qo)[(size_t)bh * SS + qt * 128 + r * 64 + ql];

    float4 acc[2];
    float  l[2];
    #pragma unroll
    for (int r = 0; r < 2; ++r) { acc[r] = make_float4(0.f, 0.f, 0.f, 0.f); l[r] = 0.f; }

    const int k0 = kq << 7;
    #pragma unroll 4
    for (int kk = k0; kk < k0 + 128; ++kk) {
        float4 kr = Ksh[kk];          // single broadcast addr per wave
        float4 vr = Vsh[kk];
        #pragma unroll
        for (int r = 0; r < 2; ++r) {
            float s = qv[r].x * kr.x + qv[r].y * kr.y + qv[r].z * kr.z + qv[r].w * kr.w;
            float p = EXP2F(s);
            l[r] += p;
            acc[r].x += p * vr.x; acc[r].y += p * vr.y;
            acc[r].z += p * vr.z; acc[r].w += p * vr.w;
        }
    }

    __syncthreads();   // all K/V reads done; smem reused as merge buffers
    #pragma unroll
    for (int r = 0; r < 2; ++r) {
        pacc[kq * 128 + r * 64 + ql] = acc[r];
        pl[kq * 128 + r * 64 + ql]   = l[r];
    }
    __syncthreads();

    // merge the 8 k-slices: threads 0..127 own query qt*128 + tid
    if (tid < 128) {
        float4 a  = pacc[tid];
        float  ll = pl[tid];
        #pragma unroll
        for (int j = 1; j < 8; ++j) {
            float4 t = pacc[j * 128 + tid];
            a.x += t.x; a.y += t.y; a.z += t.z; a.w += t.w;
            ll += pl[j * 128 + tid];
        }
        const float inv = 1.f / ll;
        const int b = bh / NH, h = bh % NH;
        const int q = qt * 128 + tid;
        ((float4*)A)[(size_t)(b * SS + q) * NH + h] =
            make_float4(a.x * inv, a.y * inv, a.z * inv, a.w * inv);
    }
}

// ---------------------------------------------------------------------------
// Kernel 3: LayerNorm(28) + FFN(28->7)+ReLU+residual -> out (output 0),
// then Q2 (row-major, pre-scaled by (1/sqrt(7))*log2e for exp2 softmax)
// and K2 TRANSPOSED: K2T[b][d][s].
// ---------------------------------------------------------------------------
__global__ __launch_bounds__(256) void k_lnffn(
    const float* __restrict__ A, const float* __restrict__ inp,
    const float* __restrict__ lnw, const float* __restrict__ lnb,
    const float* __restrict__ W1, const float* __restrict__ b1,
    const float* __restrict__ Wq2, const float* __restrict__ bq2,
    const float* __restrict__ Wk2, const float* __restrict__ bk2,
    float* __restrict__ outp, float* __restrict__ Q2, float* __restrict__ K2T)
{
    const int r = blockIdx.x * 256 + threadIdx.x;

    float y[NHID];
    const float4* Ar = (const float4*)A + (size_t)r * 7;
    float mu = 0.f;
    #pragma unroll
    for (int j4 = 0; j4 < 7; ++j4) {
        float4 t = Ar[j4];
        y[4 * j4 + 0] = t.x; y[4 * j4 + 1] = t.y; y[4 * j4 + 2] = t.z; y[4 * j4 + 3] = t.w;
        mu += t.x + t.y + t.z + t.w;
    }
    mu *= (1.f / NHID);
    float var = 0.f;
    #pragma unroll
    for (int j = 0; j < NHID; ++j) { float d = y[j] - mu; var += d * d; }
    var *= (1.f / NHID);
    const float rstd = rsqrtf(var + 1e-5f);
    #pragma unroll
    for (int j = 0; j < NHID; ++j) y[j] = (y[j] - mu) * rstd * lnw[j] + lnb[j];

    float o[NIN];
    #pragma unroll
    for (int i = 0; i < NIN; ++i) {
        float a = b1[i];
        #pragma unroll
        for (int j = 0; j < NHID; ++j) a += y[j] * W1[j * NIN + i];
        o[i] = fmaxf(a, 0.f) + inp[r * NIN + i];
        outp[r * NIN + i] = o[i];
    }

    const float rs7l2e = 0.3779644730092272f * 1.4426950408889634f;  // (1/sqrt7)*log2e
    const int b = r >> 10, s = r & 1023;
    float* K2Tb = K2T + ((size_t)b * NHID) * SS + s;
    float4* Q2r = (float4*)Q2 + (size_t)r * 7;
    #pragma unroll
    for (int j4 = 0; j4 < 7; ++j4) {
        float qq[4];
        #pragma unroll
        for (int c = 0; c < 4; ++c) {
            int j = 4 * j4 + c;
            float aq = bq2[j], ak = bk2[j];
            #pragma unroll
            for (int i = 0; i < NIN; ++i) {
                aq += o[i] * Wq2[i * NHID + j];
                ak += o[i] * Wk2[i * NHID + j];
            }
            qq[c] = aq * rs7l2e;
            K2Tb[(size_t)j * SS] = ak;      // coalesced per-j
        }
        Q2r[j4] = make_float4(qq[0], qq[1], qq[2], qq[3]);
    }
}

// ---------------------------------------------------------------------------
// Kernel 4: attention 2 weights. Wave-autonomous, 4 rows/wave; dynamic
// 28-dim loop (q via LDS scalar broadcast) + __launch_bounds__(256,4)
// keeps VGPR at the 128 cap without spill (R6: total dropped 216->187).
// exp2 softmax (Q2 pre-scaled by log2e in k_lnffn).
// ---------------------------------------------------------------------------
#define QR 4
__global__ __launch_bounds__(256, 4) void k_attn2(
    const float* __restrict__ Q2, const float* __restrict__ K2T,
    float* __restrict__ out2)
{
    __shared__ float q2s[16 * NHID];   // 1792 B

    const int tid  = threadIdx.x;
    const int lane = tid & 63;
    const int wid  = tid >> 6;
    const int row0 = blockIdx.x * 16;          // global row = b*1024 + s
    const int b    = row0 >> 10;

    if (tid < 112) ((float4*)q2s)[tid] = ((const float4*)Q2)[(size_t)row0 * 7 + tid];
    __syncthreads();

    const float*  qw  = q2s + wid * QR * NHID;              // this wave's 4 rows
    const float4* K2b = (const float4*)(K2T + (size_t)b * NHID * SS);  // [28][256] f4

    float4 p0[QR], p1[QR], p2[QR], p3[QR];     // p[r][j]: 64 VGPRs
    #pragma unroll
    for (int r = 0; r < QR; ++r) {
        p0[r] = make_float4(0.f, 0.f, 0.f, 0.f);
        p1[r] = make_float4(0.f, 0.f, 0.f, 0.f);
        p2[r] = make_float4(0.f, 0.f, 0.f, 0.f);
        p3[r] = make_float4(0.f, 0.f, 0.f, 0.f);
    }

    #pragma unroll 2
    for (int d = 0; d < NHID; ++d) {
        float4 kt0 = K2b[d * 256 +       lane];
        float4 kt1 = K2b[d * 256 +  64 + lane];
        float4 kt2 = K2b[d * 256 + 128 + lane];
        float4 kt3 = K2b[d * 256 + 192 + lane];
        #pragma unroll
        for (int r = 0; r < QR; ++r) {
            const float qd = qw[r * NHID + d];  // LDS scalar broadcast
            p0[r].x += qd * kt0.x; p0[r].y += qd * kt0.y;
            p0[r].z += qd * kt0.z; p0[r].w += qd * kt0.w;
            p1[r].x += qd * kt1.x; p1[r].y += qd * kt1.y;
            p1[r].z += qd * kt1.z; p1[r].w += qd * kt1.w;
            p2[r].x += qd * kt2.x; p2[r].y += qd * kt2.y;
            p2[r].z += qd * kt2.z; p2[r].w += qd * kt2.w;
            p3[r].x += qd * kt3.x; p3[r].y += qd * kt3.y;
            p3[r].z += qd * kt3.z; p3[r].w += qd * kt3.w;
        }
    }

    #pragma unroll
    for (int r = 0; r < QR; ++r) {
        p0[r].x = EXP2F(p0[r].x); p0[r].y = EXP2F(p0[r].y);
        p0[r].z = EXP2F(p0[r].z); p0[r].w = EXP2F(p0[r].w);
        p1[r].x = EXP2F(p1[r].x); p1[r].y = EXP2F(p1[r].y);
        p1[r].z = EXP2F(p1[r].z); p1[r].w = EXP2F(p1[r].w);
        p2[r].x = EXP2F(p2[r].x); p2[r].y = EXP2F(p2[r].y);
        p2[r].z = EXP2F(p2[r].z); p2[r].w = EXP2F(p2[r].w);
        p3[r].x = EXP2F(p3[r].x); p3[r].y = EXP2F(p3[r].y);
        p3[r].z = EXP2F(p3[r].z); p3[r].w = EXP2F(p3[r].w);
        float sum = p0[r].x + p0[r].y + p0[r].z + p0[r].w
                  + p1[r].x + p1[r].y + p1[r].z + p1[r].w
                  + p2[r].x + p2[r].y + p2[r].z + p2[r].w
                  + p3[r].x + p3[r].y + p3[r].z + p3[r].w;
        #pragma unroll
        for (int off = 1; off < 64; off <<= 1) sum += __shfl_xor(sum, off);
        const float iv = 1.f / sum;
        float4* orow = (float4*)(out2 + ((size_t)row0 + wid * QR + r) * SS);
        orow[       lane] = make_float4(p0[r].x * iv, p0[r].y * iv, p0[r].z * iv, p0[r].w * iv);
        orow[ 64 + lane] = make_float4(p1[r].x * iv, p1[r].y * iv, p1[r].z * iv, p1[r].w * iv);
        orow[128 + lane] = make_float4(p2[r].x * iv, p2[r].y * iv, p2[r].z * iv, p2[r].w * iv);
        orow[192 + lane] = make_float4(p3[r].x * iv, p3[r].y * iv, p3[r].z * iv, p3[r].w * iv);
    }
}

// ---------------------------------------------------------------------------
extern "C" void kernel_launch(void* const* d_in, const int* in_sizes, int n_in,
                              void* d_out, int out_size, void* d_ws, size_t ws_size,
                              hipStream_t stream) {
    const float* inp = (const float*)d_in[0];
    const float* Wq  = (const float*)d_in[1];
    const float* bq  = (const float*)d_in[2];
    const float* Wk  = (const float*)d_in[3];
    const float* bk  = (const float*)d_in[4];
    const float* Wv  = (const float*)d_in[5];
    const float* bv  = (const float*)d_in[6];
    const float* lnw = (const float*)d_in[7];
    const float* lnb = (const float*)d_in[8];
    const float* W1  = (const float*)d_in[9];
    const float* b1  = (const float*)d_in[10];
    const float* Wq2 = (const float*)d_in[11];
    const float* bq2 = (const float*)d_in[12];
    const float* Wk2 = (const float*)d_in[13];
    const float* bk2 = (const float*)d_in[14];

    float* out0 = (float*)d_out;                 // [16,1024,7]
    float* out2 = out0 + ROWS * NIN;             // [16,1024,1024]

    float* ws = (float*)d_ws;
    float* Qo  = ws;
    float* Ko  = ws + (size_t)QKV_ELEMS;
    float* Vo  = ws + (size_t)2 * QKV_ELEMS;
    float* A   = ws + (size_t)3 * QKV_ELEMS;
    float* Q2  = ws + (size_t)4 * QKV_ELEMS;
    float* K2T = ws + (size_t)5 * QKV_ELEMS;     // [B,28,S]

    k_proj <<<ROWS / 256, 256, 0, stream>>>(inp, Wq, bq, Wk, bk, Wv, bv, Qo, Ko, Vo);
    k_attn1<<<BB * NH * 8, 512, 0, stream>>>(Qo, Ko, Vo, A);
    k_lnffn<<<ROWS / 256, 256, 0, stream>>>(A, inp, lnw, lnb, W1, b1,
                                            Wq2, bq2, Wk2, bk2, out0, Q2, K2T);
    k_attn2<<<ROWS / 16, 256, 0, stream>>>(Q2, K2T, out2);
}